// Round 10
// baseline (75.102 us; speedup 1.0000x reference)
//
#include <hip/hip_runtime.h>

// LengthRegulator fused: x (B=32, C=384, T=1024) f32, duration (B,T) i32 in [0,8),
// max_len = 7168. Block = (batch, 4-channel group) loops all 7 frame-tiles.
// x rows staged into LDS ONCE (4 coalesced f32x4 loads/thread) -> gathers on
// the ds pipe, nt stores own the TA pipe (R9 confirmed TA contention).
// Double-buffered 2 KB u16 token maps, NO init pass: frames >= mel hold
// garbage but validity (f < mel) is register-computed, so the mask is free.
// 1 barrier per live tile. nt stores mandatory (R6: plain stores -> L2
// write-allocate, +352 MB HBM reads).
// out0 = gathered x (zero past mel_len); out1 = mel_len as f32.

#define B_ 32
#define C_ 384
#define T_ 1024
#define MAXLEN_ 7168
#define FT_ 7                     // frame tiles of 1024
#define CPB_ 4                    // channels per block
#define NT_ 256                   // threads per block
#define NCG_ (C_ / CPB_)          // 96 channel groups
#define NWG_ (NCG_ * B_)          // 3072, divisible by 8
#define NXCD_ 8

typedef float f32x4 __attribute__((ext_vector_type(4)));

__global__ __launch_bounds__(NT_) void lr_fused_kernel(
    const int* __restrict__ dur,     // (B, T)
    const float* __restrict__ x,     // (B, C, T)
    float* __restrict__ out,         // (B, C, MAXLEN)
    float* __restrict__ mel_out)     // (B,) stored as float
{
    const int tid = threadIdx.x;

    // XCD-chunked bijective swizzle (T1)
    const int bid  = blockIdx.x;
    const int wgid = (bid & (NXCD_ - 1)) * (NWG_ / NXCD_) + (bid >> 3);
    const int cblk = wgid % NCG_;
    const int b    = wgid / NCG_;

    __shared__ float s_x[CPB_][T_];              // 16 KB staged x rows
    __shared__ unsigned short s_map[2][1024];    // 2x2 KB double-buffered map
    __shared__ int s_w[NT_ / 64];

    // ---- dur load + wave-shuffle scan ----
    const int4 d4 = ((const int4*)(dur + b * T_))[tid];
    const int sum4 = d4.x + d4.y + d4.z + d4.w;

    const int lane = tid & 63;
    const int wave = tid >> 6;
    int sc = sum4;
    #pragma unroll
    for (int d = 1; d < 64; d <<= 1) {
        int n = __shfl_up(sc, d, 64);
        if (lane >= d) sc += n;
    }
    if (lane == 63) s_w[wave] = sc;

    // ---- stage 4 x rows into LDS while the scan settles ----
    const float* xb = x + ((size_t)b * C_ + cblk * CPB_) * T_;
    #pragma unroll
    for (int r = 0; r < CPB_; ++r)
        ((f32x4*)s_x[r])[tid] = ((const f32x4*)(xb + r * T_))[tid];

    __syncthreads();                              // s_w + staging visible

    int woff = 0;
    #pragma unroll
    for (int w = 0; w < NT_ / 64; ++w)
        woff += (w < wave) ? s_w[w] : 0;
    const int mel = s_w[0] + s_w[1] + s_w[2] + s_w[3];

    if (cblk == 0 && tid == 0)
        mel_out[b] = (float)mel;

    // this thread's 4 tokens (persist across tiles)
    const int st = woff + sc - sum4;              // exclusive start
    const int s0 = st;
    const int s1 = s0 + d4.x;
    const int s2 = s1 + d4.y;
    const int s3 = s2 + d4.z;
    const int send = s3 + d4.w;

    const int nvt = (mel + 1023) >> 10;           // live tiles (<= 7)

    float* ob0 = out + ((size_t)b * C_ + cblk * CPB_) * MAXLEN_ + (tid << 2);
    const int fbase = tid << 2;                   // this thread's frame offset

    // ---- live tiles: scatter -> barrier -> gather/store (1 barrier/tile) ----
    for (int ft = 0; ft < nvt; ++ft) {
        unsigned short* buf = s_map[ft & 1];
        const int f0 = ft << 10;

        if (st < f0 + 1024 && send > f0) {        // tokens overlap this tile
            const int base_tok = tid << 2;
            const int starts[4] = { s0, s1, s2, s3 };
            const int lens[4]   = { d4.x, d4.y, d4.z, d4.w };
            #pragma unroll
            for (int k = 0; k < 4; ++k) {
                int lo = starts[k] - f0;
                int hi = lo + lens[k];
                lo = lo < 0 ? 0 : lo;
                hi = hi > 1024 ? 1024 : hi;
                for (int p = lo; p < hi; ++p)
                    buf[p] = (unsigned short)(base_tok + k);
            }
        }
        __syncthreads();                          // map complete (+ prev reads done)

        const uint2 m = ((const uint2*)buf)[tid];
        const unsigned int t0 = m.x & 1023u, t1 = (m.x >> 16) & 1023u;
        const unsigned int t2 = m.y & 1023u, t3 = (m.y >> 16) & 1023u;
        const int f = f0 + fbase;
        const bool v0 = (f + 0) < mel, v1 = (f + 1) < mel;
        const bool v2 = (f + 2) < mel, v3 = (f + 3) < mel;

        float* ob = ob0 + f0;
        #pragma unroll
        for (int cc = 0; cc < CPB_; ++cc) {
            f32x4 v;
            v.x = v0 ? s_x[cc][t0] : 0.0f;
            v.y = v1 ? s_x[cc][t1] : 0.0f;
            v.z = v2 ? s_x[cc][t2] : 0.0f;
            v.w = v3 ? s_x[cc][t3] : 0.0f;
            __builtin_nontemporal_store(v, (f32x4*)(ob + (size_t)cc * MAXLEN_));
        }
    }

    // ---- dead tiles: barrier-free zero stores ----
    const f32x4 z = {0.0f, 0.0f, 0.0f, 0.0f};
    for (int ft = nvt; ft < FT_; ++ft) {
        float* ob = ob0 + (ft << 10);
        #pragma unroll
        for (int cc = 0; cc < CPB_; ++cc)
            __builtin_nontemporal_store(z, (f32x4*)(ob + (size_t)cc * MAXLEN_));
    }
}

extern "C" void kernel_launch(void* const* d_in, const int* in_sizes, int n_in,
                              void* d_out, int out_size, void* d_ws, size_t ws_size,
                              hipStream_t stream) {
    const float* x   = (const float*)d_in[0];
    const int*   dur = (const int*)d_in[1];
    // d_in[2] = max_len scalar (7168), compile-time constant here.

    float* out = (float*)d_out;
    float* mel_out = out + (size_t)B_ * C_ * MAXLEN_;  // 32 floats at the tail

    lr_fused_kernel<<<NWG_, NT_, 0, stream>>>(dur, x, out, mel_out);
}

// Round 11
// 73.130 us; speedup vs baseline: 1.0270x; 1.0270x over previous
//
#include <hip/hip_runtime.h>

// LengthRegulator, two-kernel split.
// A (32 blocks): scan duration rows once -> exclusive cumsum + total in ws,
//    mel_len (f32) to out tail.
// B (21504 blocks = ftile x cgroup x batch, XCD-swizzled): uniform L2-hit mel
//    load -> dead tiles take a pure zero-store path; live threads read their
//    4 token starts via one int4 + one dword (no scan, no dur load), scatter
//    the u16 frame->token map WITHOUT init (garbage past mel is masked by
//    register-computed f<mel validity), ONE barrier, then ds-pipe gathers +
//    nontemporal f32x4 store burst (R9: TA pipe owned by stores; R6: nt
//    mandatory else L2 write-allocate doubles write traffic).

#define B_ 32
#define C_ 384
#define T_ 1024
#define MAXLEN_ 7168
#define FT_ 7                     // frame tiles of 1024
#define CPB_ 4                    // channels per block
#define NT_ 256                   // threads per block
#define NCG_ (C_ / CPB_)          // 96 channel groups
#define NWG_ (FT_ * NCG_ * B_)    // 21504, divisible by 8
#define NXCD_ 8
#define CSTRIDE_ 1028             // ints per batch row in ws (16B-aligned)

typedef float f32x4 __attribute__((ext_vector_type(4)));

// ---------------- Kernel A: scan durations once ----------------
__global__ __launch_bounds__(NT_) void lr_scan_kernel(
    const int* __restrict__ dur,     // (B, T)
    int* __restrict__ csum,          // (B, CSTRIDE_) exclusive starts + total
    float* __restrict__ mel_out)     // (B,) as float
{
    const int b = blockIdx.x;
    const int tid = threadIdx.x;
    __shared__ int s_w[NT_ / 64];

    const int4 d4 = ((const int4*)(dur + b * T_))[tid];
    const int sum4 = d4.x + d4.y + d4.z + d4.w;

    const int lane = tid & 63;
    const int wave = tid >> 6;
    int sc = sum4;
    #pragma unroll
    for (int d = 1; d < 64; d <<= 1) {
        int n = __shfl_up(sc, d, 64);
        if (lane >= d) sc += n;
    }
    if (lane == 63) s_w[wave] = sc;
    __syncthreads();

    int woff = 0;
    #pragma unroll
    for (int w = 0; w < NT_ / 64; ++w)
        woff += (w < wave) ? s_w[w] : 0;

    const int e0 = woff + sc - sum4;         // exclusive start of token 4*tid
    int4 e;
    e.x = e0;
    e.y = e0 + d4.x;
    e.z = e.y + d4.y;
    e.w = e.z + d4.z;
    ((int4*)(csum + b * CSTRIDE_))[tid] = e;

    if (tid == NT_ - 1) {
        const int mel = e.w + d4.w;          // total frames
        csum[b * CSTRIDE_ + T_] = mel;
        mel_out[b] = (float)mel;
    }
}

// ---------------- Kernel B: scatter map + gather + nt stores ----------------
__global__ __launch_bounds__(NT_) void lr_gather_kernel(
    const int* __restrict__ csum,    // (B, CSTRIDE_)
    const float* __restrict__ x,     // (B, C, T)
    float* __restrict__ out)         // (B, C, MAXLEN)
{
    const int tid = threadIdx.x;

    // XCD-chunked bijective swizzle (T1): 7 ftiles of a slab -> same XCD L2
    const int bid  = blockIdx.x;
    const int wgid = (bid & (NXCD_ - 1)) * (NWG_ / NXCD_) + (bid >> 3);
    const int ftile = wgid % FT_;
    const int rest  = wgid / FT_;
    const int cblk  = rest % NCG_;
    const int b     = rest / NCG_;
    const int f0    = ftile << 10;

    const int mel = csum[b * CSTRIDE_ + T_];      // uniform -> s_load, L2-hit

    float* ob = out + ((size_t)b * C_ + cblk * CPB_) * MAXLEN_ + f0 + (tid << 2);

    // ---- dead tile: pure zero-store path, no scan/stage/barriers ----
    if (f0 >= mel) {
        const f32x4 z = {0.0f, 0.0f, 0.0f, 0.0f};
        #pragma unroll
        for (int cc = 0; cc < CPB_; ++cc)
            __builtin_nontemporal_store(z, (f32x4*)(ob + (size_t)cc * MAXLEN_));
        return;
    }

    __shared__ float s_x[CPB_][T_];               // 16 KB staged x rows
    __shared__ unsigned short s_map[1024];        // 2 KB map, NO init needed

    // ---- stage 4 x rows into LDS (coalesced f32x4) ----
    const float* xb = x + ((size_t)b * C_ + cblk * CPB_) * T_;
    #pragma unroll
    for (int r = 0; r < CPB_; ++r)
        ((f32x4*)s_x[r])[tid] = ((const f32x4*)(xb + r * T_))[tid];

    // ---- this thread's 4 token starts + neighbor start (lens by diff) ----
    const int4 e = ((const int4*)(csum + b * CSTRIDE_))[tid];
    const int e4 = csum[b * CSTRIDE_ + (tid << 2) + 4];

    // ---- scatter tokens overlapping this tile (no init: f<mel masks rest) ----
    if (e.x < f0 + 1024 && e4 > f0) {
        const int base_tok = tid << 2;
        const int starts[4] = { e.x, e.y, e.z, e.w };
        const int ends[4]   = { e.y, e.z, e.w, e4 };
        #pragma unroll
        for (int k = 0; k < 4; ++k) {
            int lo = starts[k] - f0;
            int hi = ends[k] - f0;
            lo = lo < 0 ? 0 : lo;
            hi = hi > 1024 ? 1024 : hi;
            for (int p = lo; p < hi; ++p)
                s_map[p] = (unsigned short)(base_tok + k);
        }
    }
    __syncthreads();                              // single barrier

    // ---- gather from LDS (ds pipe), nt-store burst (TA pipe) ----
    const uint2 m = ((const uint2*)s_map)[tid];
    const unsigned int t0 = m.x & 1023u, t1 = (m.x >> 16) & 1023u;
    const unsigned int t2 = m.y & 1023u, t3 = (m.y >> 16) & 1023u;
    const int f = f0 + (tid << 2);
    const bool v0 = (f + 0) < mel, v1 = (f + 1) < mel;
    const bool v2 = (f + 2) < mel, v3 = (f + 3) < mel;

    #pragma unroll
    for (int cc = 0; cc < CPB_; ++cc) {
        f32x4 v;
        v.x = v0 ? s_x[cc][t0] : 0.0f;
        v.y = v1 ? s_x[cc][t1] : 0.0f;
        v.z = v2 ? s_x[cc][t2] : 0.0f;
        v.w = v3 ? s_x[cc][t3] : 0.0f;
        __builtin_nontemporal_store(v, (f32x4*)(ob + (size_t)cc * MAXLEN_));
    }
}

extern "C" void kernel_launch(void* const* d_in, const int* in_sizes, int n_in,
                              void* d_out, int out_size, void* d_ws, size_t ws_size,
                              hipStream_t stream) {
    const float* x   = (const float*)d_in[0];
    const int*   dur = (const int*)d_in[1];
    // d_in[2] = max_len scalar (7168), compile-time constant here.

    float* out = (float*)d_out;
    float* mel_out = out + (size_t)B_ * C_ * MAXLEN_;  // 32 floats at the tail
    int* csum = (int*)d_ws;                            // 32*1028*4 = 131.6 KB

    lr_scan_kernel<<<B_, NT_, 0, stream>>>(dur, csum, mel_out);
    lr_gather_kernel<<<NWG_, NT_, 0, stream>>>(csum, x, out);
}

// Round 12
// 69.757 us; speedup vs baseline: 1.0766x; 1.0484x over previous
//
#include <hip/hip_runtime.h>

// LengthRegulator fused (R9 structure + token-range staging).
// Block = (frame tile, 4-channel group, batch), 1D grid + XCD swizzle.
// In-block scan (VALU = free; R11 proved replacing it with csum loads = TA ops
// regresses). Block computes its live token range [t_lo,t_hi) via LDS
// atomicMin/Max from scan registers, stages ONLY that range of x into LDS
// (~1.3 f32x4 loads/thread vs 4), gathers on the ds pipe, nt f32x4 store
// burst owns the TA pipe (R9: TA contention confirmed; R6: nt mandatory else
// L2 write-allocate doubles write traffic). No map init: frames >= mel hold
// garbage, masked by register-computed f<mel (R10/R11 proven).
// out0 = gathered x (zero past mel_len); out1 = mel_len as f32.

#define B_ 32
#define C_ 384
#define T_ 1024
#define MAXLEN_ 7168
#define FT_ 7                     // frame tiles of 1024
#define CPB_ 4                    // channels per block
#define NT_ 256                   // threads per block
#define NCG_ (C_ / CPB_)          // 96 channel groups
#define NWG_ (FT_ * NCG_ * B_)    // 21504, divisible by 8
#define NXCD_ 8

typedef float f32x4 __attribute__((ext_vector_type(4)));

__global__ __launch_bounds__(NT_) void lr_fused_kernel(
    const int* __restrict__ dur,     // (B, T)
    const float* __restrict__ x,     // (B, C, T)
    float* __restrict__ out,         // (B, C, MAXLEN)
    float* __restrict__ mel_out)     // (B,) stored as float
{
    const int tid = threadIdx.x;

    // XCD-chunked bijective swizzle (T1)
    const int bid  = blockIdx.x;
    const int wgid = (bid & (NXCD_ - 1)) * (NWG_ / NXCD_) + (bid >> 3);
    const int ftile = wgid % FT_;
    const int rest  = wgid / FT_;
    const int cblk  = rest % NCG_;
    const int b     = rest / NCG_;
    const int f0    = ftile << 10;

    __shared__ float s_x[CPB_][T_];            // 16 KB staged x (token range)
    __shared__ unsigned short s_map[1024];     // 2 KB map, no init needed
    __shared__ int s_w[NT_ / 64];
    __shared__ int s_tlo, s_thi;

    // ---- dur load + wave-shuffle scan (VALU: free) ----
    const int4 d4 = ((const int4*)(dur + b * T_))[tid];
    const int sum4 = d4.x + d4.y + d4.z + d4.w;

    const int lane = tid & 63;
    const int wave = tid >> 6;
    int sc = sum4;
    #pragma unroll
    for (int d = 1; d < 64; d <<= 1) {
        int n = __shfl_up(sc, d, 64);
        if (lane >= d) sc += n;
    }
    if (lane == 63) s_w[wave] = sc;
    if (tid == 0) { s_tlo = T_; s_thi = 0; }
    __syncthreads();                            // barrier 1

    int woff = 0;
    #pragma unroll
    for (int w = 0; w < NT_ / 64; ++w)
        woff += (w < wave) ? s_w[w] : 0;
    const int mel = s_w[0] + s_w[1] + s_w[2] + s_w[3];

    if (ftile == 0 && cblk == 0 && tid == 0)
        mel_out[b] = (float)mel;

    float* ob = out + ((size_t)b * C_ + cblk * CPB_) * MAXLEN_ + f0 + (tid << 2);

    // ---- dead tile (block-uniform): zero stores only ----
    if (f0 >= mel) {
        const f32x4 z = {0.0f, 0.0f, 0.0f, 0.0f};
        #pragma unroll
        for (int cc = 0; cc < CPB_; ++cc)
            __builtin_nontemporal_store(z, (f32x4*)(ob + (size_t)cc * MAXLEN_));
        return;
    }

    // this thread's 4 token boundaries
    const int s0 = woff + sc - sum4;            // exclusive start
    const int s1 = s0 + d4.x;
    const int s2 = s1 + d4.y;
    const int s3 = s2 + d4.z;
    const int send = s3 + d4.w;
    const int base_tok = tid << 2;

    // ---- scatter tokens overlapping this tile (absolute u16 ids) ----
    if (s0 < f0 + 1024 && send > f0) {
        const int starts[4] = { s0, s1, s2, s3 };
        const int ends[4]   = { s1, s2, s3, send };
        #pragma unroll
        for (int k = 0; k < 4; ++k) {
            int lo = starts[k] - f0;
            int hi = ends[k] - f0;
            lo = lo < 0 ? 0 : lo;
            hi = hi > 1024 ? 1024 : hi;
            for (int p = lo; p < hi; ++p)
                s_map[p] = (unsigned short)(base_tok + k);
        }
    }

    // ---- token range of this tile: t_lo = token containing f0,
    //      t_hi = token containing last valid frame f1, +1 ----
    const int f1 = (f0 + 1023 < mel - 1) ? (f0 + 1023) : (mel - 1);
    if (s0 <= f0 && send > f0) {               // exactly one thread
        const int k = (s1 > f0) ? 0 : (s2 > f0) ? 1 : (s3 > f0) ? 2 : 3;
        atomicMin(&s_tlo, base_tok + k);
    }
    if (s0 <= f1 && send > f1) {               // exactly one thread
        const int k = (s1 > f1) ? 0 : (s2 > f1) ? 1 : (s3 > f1) ? 2 : 3;
        atomicMax(&s_thi, base_tok + k + 1);
    }
    __syncthreads();                            // barrier 2: map + range done

    // ---- stage ONLY x[t0a .. t_hi) rows into LDS (16B-aligned start) ----
    const int t0a = s_tlo & ~3;                 // align down to f32x4
    const int nv  = (s_thi - t0a + 3) >> 2;     // f32x4 count (<= 256)
    const float* xb = x + ((size_t)b * C_ + cblk * CPB_) * T_;
    #pragma unroll
    for (int r = 0; r < CPB_; ++r) {
        const f32x4* __restrict__ src = (const f32x4*)(xb + r * T_ + t0a);
        f32x4* dst = (f32x4*)s_x[r];
        for (int i = tid; i < nv; i += NT_)
            dst[i] = src[i];
    }
    __syncthreads();                            // barrier 3: staging done

    // ---- gather from LDS (ds pipe), nt-store burst (TA pipe) ----
    const uint2 m = ((const uint2*)s_map)[tid];
    const unsigned int t0 = (( m.x        & 0xFFFFu) - t0a) & 1023u;
    const unsigned int t1 = (( m.x >> 16)           - t0a) & 1023u;
    const unsigned int t2 = (( m.y        & 0xFFFFu) - t0a) & 1023u;
    const unsigned int t3 = (( m.y >> 16)           - t0a) & 1023u;
    const int f = f0 + (tid << 2);
    const bool v0 = (f + 0) < mel, v1 = (f + 1) < mel;
    const bool v2 = (f + 2) < mel, v3 = (f + 3) < mel;

    #pragma unroll
    for (int cc = 0; cc < CPB_; ++cc) {
        f32x4 v;
        v.x = v0 ? s_x[cc][t0] : 0.0f;
        v.y = v1 ? s_x[cc][t1] : 0.0f;
        v.z = v2 ? s_x[cc][t2] : 0.0f;
        v.w = v3 ? s_x[cc][t3] : 0.0f;
        __builtin_nontemporal_store(v, (f32x4*)(ob + (size_t)cc * MAXLEN_));
    }
}

extern "C" void kernel_launch(void* const* d_in, const int* in_sizes, int n_in,
                              void* d_out, int out_size, void* d_ws, size_t ws_size,
                              hipStream_t stream) {
    const float* x   = (const float*)d_in[0];
    const int*   dur = (const int*)d_in[1];
    // d_in[2] = max_len scalar (7168), compile-time constant here.

    float* out = (float*)d_out;
    float* mel_out = out + (size_t)B_ * C_ * MAXLEN_;  // 32 floats at the tail

    lr_fused_kernel<<<NWG_, NT_, 0, stream>>>(dur, x, out, mel_out);
}

// Round 13
// 67.862 us; speedup vs baseline: 1.1067x; 1.0279x over previous
//
#include <hip/hip_runtime.h>

// LengthRegulator fused — R9 structure (best: 67.4 us) + no-map-init.
// Block = (frame tile, 4-channel group, batch), 1D grid + XCD swizzle.
// x rows staged into LDS (coalesced f32x4) -> gathers on the ds pipe, so the
// nontemporal f32x4 store burst owns the TA pipe (R9: TA load/store issue
// contention confirmed, +7%). nt stores mandatory (R6: plain stores trigger
// L2 write-allocate, +352 MB HBM reads). No map init: frames >= mel hold
// garbage, masked by register-computed f < mel (proven R10-R12).
// In-block scan kept (VALU is free; R11 proved csum loads = TA ops regress).
// out0 = gathered x (zero past mel_len); out1 = mel_len as f32.

#define B_ 32
#define C_ 384
#define T_ 1024
#define MAXLEN_ 7168
#define FT_ 7                     // frame tiles of 1024
#define CPB_ 4                    // channels per block
#define NT_ 256                   // threads per block
#define NCG_ (C_ / CPB_)          // 96 channel groups
#define NWG_ (FT_ * NCG_ * B_)    // 21504, divisible by 8
#define NXCD_ 8

typedef float f32x4 __attribute__((ext_vector_type(4)));

__global__ __launch_bounds__(NT_) void lr_fused_kernel(
    const int* __restrict__ dur,     // (B, T)
    const float* __restrict__ x,     // (B, C, T)
    float* __restrict__ out,         // (B, C, MAXLEN)
    float* __restrict__ mel_out)     // (B,) stored as float
{
    const int tid = threadIdx.x;

    // XCD-chunked bijective swizzle (T1)
    const int bid  = blockIdx.x;
    const int wgid = (bid & (NXCD_ - 1)) * (NWG_ / NXCD_) + (bid >> 3);
    const int ftile = wgid % FT_;
    const int rest  = wgid / FT_;
    const int cblk  = rest % NCG_;
    const int b     = rest / NCG_;
    const int f0    = ftile << 10;

    __shared__ float s_x[CPB_][T_];            // 16 KB staged x rows
    __shared__ unsigned short s_map[1024];     // 2 KB frame->token map, NO init
    __shared__ int s_w[NT_ / 64];

    // ---- dur load + wave-shuffle scan (VALU: free) ----
    const int4 d4 = ((const int4*)(dur + b * T_))[tid];
    const int sum4 = d4.x + d4.y + d4.z + d4.w;

    const int lane = tid & 63;
    const int wave = tid >> 6;
    int sc = sum4;
    #pragma unroll
    for (int d = 1; d < 64; d <<= 1) {
        int n = __shfl_up(sc, d, 64);
        if (lane >= d) sc += n;
    }
    if (lane == 63) s_w[wave] = sc;
    __syncthreads();                            // barrier 1: s_w visible

    int woff = 0;
    #pragma unroll
    for (int w = 0; w < NT_ / 64; ++w)
        woff += (w < wave) ? s_w[w] : 0;
    const int mel = s_w[0] + s_w[1] + s_w[2] + s_w[3];

    if (ftile == 0 && cblk == 0 && tid == 0)
        mel_out[b] = (float)mel;

    float* ob = out + ((size_t)b * C_ + cblk * CPB_) * MAXLEN_ + f0 + (tid << 2);

    // ---- dead tile (block-uniform): zero stores only, no further barriers ----
    if (f0 >= mel) {
        const f32x4 z = {0.0f, 0.0f, 0.0f, 0.0f};
        #pragma unroll
        for (int cc = 0; cc < CPB_; ++cc)
            __builtin_nontemporal_store(z, (f32x4*)(ob + (size_t)cc * MAXLEN_));
        return;
    }

    // ---- stage 4 x rows into LDS: 4 coalesced f32x4 loads per thread ----
    const float* xb = x + ((size_t)b * C_ + cblk * CPB_) * T_;
    #pragma unroll
    for (int r = 0; r < CPB_; ++r)
        ((f32x4*)s_x[r])[tid] = ((const f32x4*)(xb + r * T_))[tid];

    // ---- scatter this thread's 4 tokens into the tile map ----
    {
        const int st = woff + sc - sum4;        // exclusive start
        const int s0 = st;
        const int s1 = s0 + d4.x;
        const int s2 = s1 + d4.y;
        const int s3 = s2 + d4.z;
        const int send = s3 + d4.w;
        if (s0 < f0 + 1024 && send > f0) {      // tokens overlap this tile
            const int base_tok = tid << 2;
            const int starts[4] = { s0, s1, s2, s3 };
            const int ends[4]   = { s1, s2, s3, send };
            #pragma unroll
            for (int k = 0; k < 4; ++k) {
                int lo = starts[k] - f0;
                int hi = ends[k] - f0;
                lo = lo < 0 ? 0 : lo;
                hi = hi > 1024 ? 1024 : hi;
                for (int p = lo; p < hi; ++p)
                    s_map[p] = (unsigned short)(base_tok + k);
            }
        }
    }
    __syncthreads();                            // barrier 2: staging + map done

    // ---- gather from LDS (ds pipe), nt-store burst (TA pipe) ----
    const uint2 m = ((const uint2*)s_map)[tid]; // tokens for frames tid*4..+3
    const unsigned int t0 = m.x & 1023u, t1 = (m.x >> 16) & 1023u;
    const unsigned int t2 = m.y & 1023u, t3 = (m.y >> 16) & 1023u;
    const int f = f0 + (tid << 2);
    const bool v0 = (f + 0) < mel, v1 = (f + 1) < mel;
    const bool v2 = (f + 2) < mel, v3 = (f + 3) < mel;

    #pragma unroll
    for (int cc = 0; cc < CPB_; ++cc) {
        f32x4 v;
        v.x = v0 ? s_x[cc][t0] : 0.0f;
        v.y = v1 ? s_x[cc][t1] : 0.0f;
        v.z = v2 ? s_x[cc][t2] : 0.0f;
        v.w = v3 ? s_x[cc][t3] : 0.0f;
        __builtin_nontemporal_store(v, (f32x4*)(ob + (size_t)cc * MAXLEN_));
    }
}

extern "C" void kernel_launch(void* const* d_in, const int* in_sizes, int n_in,
                              void* d_out, int out_size, void* d_ws, size_t ws_size,
                              hipStream_t stream) {
    const float* x   = (const float*)d_in[0];
    const int*   dur = (const int*)d_in[1];
    // d_in[2] = max_len scalar (7168), compile-time constant here.

    float* out = (float*)d_out;
    float* mel_out = out + (size_t)B_ * C_ * MAXLEN_;  // 32 floats at the tail

    lr_fused_kernel<<<NWG_, NT_, 0, stream>>>(dur, x, out, mel_out);
}